// Round 3
// baseline (1575.241 us; speedup 1.0000x reference)
//
#include <hip/hip_runtime.h>
#include <hip/hip_bf16.h>

#define EPSF 1e-5f
#define IOU_THRF 0.9f
#define NBOX 9216
#define NWORDS 144   // 9216/64

// ---------------- depthwise 3x3 conv, C=256, 32x32, pad 1 ----------------
__global__ __launch_bounds__(256) void dw_conv(const float* __restrict__ x,
                                               const float* __restrict__ w,
                                               float* __restrict__ h0) {
    int idx = blockIdx.x * 256 + threadIdx.x;   // 262144 threads
    int c = idx >> 10, p = idx & 1023;
    int yy = p >> 5, xx = p & 31;
    const float* xi = x + (c << 10);
    const float* wc = w + c * 9;
    float acc = 0.f;
    #pragma unroll
    for (int dy = -1; dy <= 1; ++dy) {
        int y2 = yy + dy;
        if ((unsigned)y2 >= 32u) continue;
        #pragma unroll
        for (int dx = -1; dx <= 1; ++dx) {
            int x2 = xx + dx;
            if ((unsigned)x2 >= 32u) continue;
            acc += wc[(dy + 1) * 3 + (dx + 1)] * xi[y2 * 32 + x2];
        }
    }
    h0[idx] = acc;
}

// ---------------- pointwise 256x256 GEMM + BN1 + leaky relu ----------------
__global__ __launch_bounds__(256) void pw_conv(const float* __restrict__ h0,
                                               const float* __restrict__ w,
                                               const float* __restrict__ g,
                                               const float* __restrict__ b,
                                               const float* __restrict__ mu,
                                               const float* __restrict__ var,
                                               float* __restrict__ h1) {
    int p = blockIdx.x * 256 + threadIdx.x;
    int o0 = blockIdx.y * 4;
    float acc0 = 0.f, acc1 = 0.f, acc2 = 0.f, acc3 = 0.f;
    for (int c = 0; c < 256; ++c) {
        float hv = h0[(c << 10) + p];
        acc0 += w[(o0 + 0) * 256 + c] * hv;
        acc1 += w[(o0 + 1) * 256 + c] * hv;
        acc2 += w[(o0 + 2) * 256 + c] * hv;
        acc3 += w[(o0 + 3) * 256 + c] * hv;
    }
    float accs[4] = {acc0, acc1, acc2, acc3};
    #pragma unroll
    for (int k = 0; k < 4; ++k) {
        int o = o0 + k;
        float inv = 1.0f / sqrtf(var[o] + EPSF);
        float v = (accs[k] - mu[o]) * (inv * g[o]) + b[o];
        v = (v >= 0.f) ? v : 0.01f * v;
        h1[(o << 10) + p] = v;
    }
}

// ---------------- heads: anc (36 ch) + obj (9 ch) GEMV + BN + decode ----------------
__global__ __launch_bounds__(256) void heads(const float* __restrict__ h1,
                                             const float* __restrict__ anc_w,
                                             const float* __restrict__ ag,
                                             const float* __restrict__ ab,
                                             const float* __restrict__ am,
                                             const float* __restrict__ av,
                                             const float* __restrict__ obj_w,
                                             const float* __restrict__ og,
                                             const float* __restrict__ ob,
                                             const float* __restrict__ om,
                                             const float* __restrict__ ov,
                                             const float* __restrict__ anchors,
                                             float* __restrict__ boxes,
                                             float* __restrict__ scores) {
    int p = blockIdx.x * 256 + threadIdx.x;
    int o = blockIdx.y;
    const float* wrow = (o < 36) ? (anc_w + o * 256) : (obj_w + (o - 36) * 256);
    float acc = 0.f;
    for (int c = 0; c < 256; ++c) acc += wrow[c] * h1[(c << 10) + p];
    if (o < 36) {
        float inv = 1.0f / sqrtf(av[o] + EPSF);
        float v = (acc - am[o]) * (inv * ag[o]) + ab[o];
        v = fminf(fmaxf(v, 0.f), 6.f);           // clip 0..6
        int a = o >> 2, k = o & 3;
        float anch = anchors[a * 4 + k];
        float val = (k < 2) ? (v + anch) : (expf(v) * anch);
        boxes[(size_t)(a * 1024 + p) * 4 + k] = val;
    } else {
        int a = o - 36;
        float inv = 1.0f / sqrtf(ov[a] + EPSF);
        float v = (acc - om[a]) * (inv * og[a]) + ob[a];
        scores[a * 1024 + p] = 1.0f / (1.0f + expf(-v));
    }
}

// ---------------- rank = stable-descending-argsort position, O(N^2) count ----------------
__global__ __launch_bounds__(256) void rank_partial(const float* __restrict__ scores,
                                                    unsigned* __restrict__ rank) {
    __shared__ float4 sm[288];
    int mbase = blockIdx.y * 1152;
    for (int t = threadIdx.x; t < 288; t += 256)
        sm[t] = ((const float4*)(scores + mbase))[t];
    __syncthreads();
    int n = blockIdx.x * 256 + threadIdx.x;
    float s = scores[n];
    unsigned cnt = 0;
    for (int q = 0; q < 288; ++q) {
        float4 v = sm[q];
        int m = mbase + q * 4;
        cnt += (v.x > s) || (v.x == s && (m + 0) < n);
        cnt += (v.y > s) || (v.y == s && (m + 1) < n);
        cnt += (v.z > s) || (v.z == s && (m + 2) < n);
        cnt += (v.w > s) || (v.w == s && (m + 3) < n);
    }
    atomicAdd(&rank[n], cnt);
}

// ---------------- scatter into sorted order ----------------
__global__ __launch_bounds__(256) void scatter_sorted(const float* __restrict__ boxes,
                                                      const unsigned* __restrict__ rank,
                                                      int* __restrict__ order,
                                                      float* __restrict__ sboxes,
                                                      float* __restrict__ sareas) {
    int n = blockIdx.x * 256 + threadIdx.x;
    unsigned r = rank[n];
    order[r] = n;
    float4 bx = ((const float4*)boxes)[n];
    ((float4*)sboxes)[r] = bx;
    sareas[r] = (bx.z - bx.x) * (bx.w - bx.y);
}

// ---------------- suppression bitmask, [word][row] layout ----------------
__global__ __launch_bounds__(256) void build_mask(const float* __restrict__ sboxes,
                                                  const float* __restrict__ sareas,
                                                  unsigned long long* __restrict__ mask,
                                                  unsigned* __restrict__ rownz) {
    __shared__ float X1[64], Y1[64], X2[64], Y2[64], AR[64];
    int wj = blockIdx.x;
    int i = blockIdx.y * 256 + threadIdx.x;
    int j0 = wj * 64;
    if (threadIdx.x < 64) {
        int j = j0 + threadIdx.x;
        float4 b = ((const float4*)sboxes)[j];
        X1[threadIdx.x] = b.x; Y1[threadIdx.x] = b.y;
        X2[threadIdx.x] = b.z; Y2[threadIdx.x] = b.w;
        AR[threadIdx.x] = sareas[j];
    }
    __syncthreads();
    unsigned long long wbits = 0ull;
    if (j0 + 63 > i) {   // word has at least one column j > i
        float4 b = ((const float4*)sboxes)[i];
        float ar = sareas[i];
        #pragma unroll 8
        for (int t = 0; t < 64; ++t) {
            float ix = fminf(b.z, X2[t]) - fmaxf(b.x, X1[t]);
            float iy = fminf(b.w, Y2[t]) - fmaxf(b.y, Y1[t]);
            float inter = fmaxf(ix, 0.f) * fmaxf(iy, 0.f);
            float iou = inter / (ar + AR[t] - inter);
            if (iou > IOU_THRF && (j0 + t) > i) wbits |= (1ull << t);
        }
    }
    mask[(size_t)wj * NBOX + i] = wbits;
    if (wbits) atomicOr(&rownz[i], 1u);
}

// ---------------- serial greedy scan over COMPACTED row list ----------------
// Only rows with outgoing suppression edges (rownz) can modify remv; rows
// without edges never affect the scan and their alive bit is read in finalize.
__device__ inline unsigned long long shfl_u64(unsigned long long v, int src) {
    int lo = __shfl((int)(unsigned)(v & 0xffffffffull), src, 64);
    int hi = __shfl((int)(unsigned)(v >> 32), src, 64);
    return ((unsigned long long)(unsigned)hi << 32) | (unsigned)lo;
}

struct Row3 { unsigned long long a, b, c; };

__global__ __launch_bounds__(64) void nms_scan(const unsigned long long* __restrict__ mask,
                                               const unsigned* __restrict__ rownz,
                                               unsigned long long* __restrict__ remv_out) {
    __shared__ unsigned short list[NBOX];
    int lane = threadIdx.x;

    // --- compact sorted indices with rownz != 0 (order-preserving) ---
    unsigned cnt = 0;
    for (int base = 0; base < NBOX; base += 64) {
        bool f = rownz[base + lane] != 0u;
        unsigned long long bal = __ballot(f);
        if (f) {
            unsigned pos = cnt + (unsigned)__popcll(bal & ((1ull << lane) - 1ull));
            list[pos] = (unsigned short)(base + lane);
        }
        cnt += (unsigned)__popcll(bal);
    }
    __syncthreads();

    unsigned long long r0 = 0ull, r1 = 0ull, r2 = 0ull;

    if (cnt > 0) {
        int icnt = (int)cnt;
        // speculative prefetch of mask rows, depth 4, named buffers (no
        // runtime-indexed register arrays -> no scratch)
        auto loadrow = [&](int kk) -> Row3 {
            int kc = kk < icnt ? kk : icnt - 1;
            int i = list[kc];
            Row3 r;
            r.a = mask[(size_t)lane * NBOX + i];
            r.b = mask[(size_t)(lane + 64) * NBOX + i];
            int l2 = (lane < 16) ? (lane + 128) : 143;
            unsigned long long t = mask[(size_t)l2 * NBOX + i];
            r.c = (lane < 16) ? t : 0ull;
            return r;
        };
        Row3 bA = loadrow(0), bB = loadrow(1), bC = loadrow(2), bD = loadrow(3);

        auto step = [&](int kk, Row3& buf) {
            if (kk < icnt) {
                int i = list[kk];
                int wi = i >> 6, slot = wi >> 6, src = wi & 63;
                unsigned long long w = (slot == 0) ? r0 : ((slot == 1) ? r1 : r2);
                w = shfl_u64(w, src);
                if (((w >> (i & 63)) & 1ull) == 0ull) {
                    r0 |= buf.a; r1 |= buf.b; r2 |= buf.c;
                }
            }
            buf = loadrow(kk + 4);
        };

        for (int k = 0; k < icnt; k += 4) {
            step(k + 0, bA);
            step(k + 1, bB);
            step(k + 2, bC);
            step(k + 3, bD);
        }
    }

    remv_out[lane] = r0;
    remv_out[lane + 64] = r1;
    if (lane < 16) remv_out[lane + 128] = r2;
}

// ---------------- finalize: out[n] = {boxes*m, score*m} ----------------
__global__ __launch_bounds__(256) void finalize(const float* __restrict__ boxes,
                                                const float* __restrict__ scores,
                                                const int* __restrict__ order,
                                                const unsigned long long* __restrict__ remv,
                                                float* __restrict__ out) {
    int i = blockIdx.x * 256 + threadIdx.x;    // sorted index
    bool alive = ((remv[i >> 6] >> (i & 63)) & 1ull) == 0ull;
    int n = order[i];
    float m = alive ? 1.f : 0.f;
    float4 b = ((const float4*)boxes)[n];
    out[(size_t)n * 5 + 0] = b.x * m;
    out[(size_t)n * 5 + 1] = b.y * m;
    out[(size_t)n * 5 + 2] = b.z * m;
    out[(size_t)n * 5 + 3] = b.w * m;
    out[(size_t)n * 5 + 4] = scores[n] * m;
}

extern "C" void kernel_launch(void* const* d_in, const int* in_sizes, int n_in,
                              void* d_out, int out_size, void* d_ws, size_t ws_size,
                              hipStream_t stream) {
    const float* x      = (const float*)d_in[0];
    const float* anchors= (const float*)d_in[1];
    const float* dw_w   = (const float*)d_in[2];
    const float* pw_w   = (const float*)d_in[3];
    const float* bn1g   = (const float*)d_in[4];
    const float* bn1b   = (const float*)d_in[5];
    const float* bn1m   = (const float*)d_in[6];
    const float* bn1v   = (const float*)d_in[7];
    const float* anc_w  = (const float*)d_in[8];
    const float* ag     = (const float*)d_in[9];
    const float* ab     = (const float*)d_in[10];
    const float* am     = (const float*)d_in[11];
    const float* av     = (const float*)d_in[12];
    const float* obj_w  = (const float*)d_in[13];
    const float* og     = (const float*)d_in[14];
    const float* ob     = (const float*)d_in[15];
    const float* om     = (const float*)d_in[16];
    const float* ov     = (const float*)d_in[17];
    float* out = (float*)d_out;

    char* ws = (char*)d_ws;
    size_t off = 0;
    auto alloc = [&](size_t bytes) -> char* {
        char* p = ws + off;
        off = (off + bytes + 255) & ~(size_t)255;
        return p;
    };
    float* h0      = (float*)alloc(256 * 1024 * 4);
    float* h1      = (float*)alloc(256 * 1024 * 4);
    float* boxes   = (float*)alloc(NBOX * 4 * 4);
    float* scores  = (float*)alloc(NBOX * 4);
    unsigned* rank = (unsigned*)alloc(NBOX * 4);
    unsigned* rownz= (unsigned*)alloc(NBOX * 4);
    int* order     = (int*)alloc(NBOX * 4);
    float* sboxes  = (float*)alloc(NBOX * 4 * 4);
    float* sareas  = (float*)alloc(NBOX * 4);
    unsigned long long* remv = (unsigned long long*)alloc(NWORDS * 8);
    unsigned long long* mask = (unsigned long long*)alloc((size_t)NBOX * NWORDS * 8);

    hipMemsetAsync(rank, 0, NBOX * 4, stream);
    hipMemsetAsync(rownz, 0, NBOX * 4, stream);

    dw_conv<<<1024, 256, 0, stream>>>(x, dw_w, h0);
    pw_conv<<<dim3(4, 64), 256, 0, stream>>>(h0, pw_w, bn1g, bn1b, bn1m, bn1v, h1);
    heads<<<dim3(4, 45), 256, 0, stream>>>(h1, anc_w, ag, ab, am, av,
                                           obj_w, og, ob, om, ov, anchors, boxes, scores);
    rank_partial<<<dim3(36, 8), 256, 0, stream>>>(scores, rank);
    scatter_sorted<<<36, 256, 0, stream>>>(boxes, rank, order, sboxes, sareas);
    build_mask<<<dim3(NWORDS, 36), 256, 0, stream>>>(sboxes, sareas, mask, rownz);
    nms_scan<<<1, 64, 0, stream>>>(mask, rownz, remv);
    finalize<<<36, 256, 0, stream>>>(boxes, scores, order, remv, out);
}

// Round 4
// 677.740 us; speedup vs baseline: 2.3243x; 2.3243x over previous
//
#include <hip/hip_runtime.h>
#include <hip/hip_bf16.h>

#define EPSF 1e-5f
#define IOU_THRF 0.9f
#define NBOX 9216
#define NWORDS 144   // 9216/64

// ---------------- depthwise 3x3 conv, C=256, 32x32, pad 1 ----------------
__global__ __launch_bounds__(256) void dw_conv(const float* __restrict__ x,
                                               const float* __restrict__ w,
                                               float* __restrict__ h0) {
    int idx = blockIdx.x * 256 + threadIdx.x;   // 262144 threads
    int c = idx >> 10, p = idx & 1023;
    int yy = p >> 5, xx = p & 31;
    const float* xi = x + (c << 10);
    const float* wc = w + c * 9;
    float acc = 0.f;
    #pragma unroll
    for (int dy = -1; dy <= 1; ++dy) {
        int y2 = yy + dy;
        if ((unsigned)y2 >= 32u) continue;
        #pragma unroll
        for (int dx = -1; dx <= 1; ++dx) {
            int x2 = xx + dx;
            if ((unsigned)x2 >= 32u) continue;
            acc += wc[(dy + 1) * 3 + (dx + 1)] * xi[y2 * 32 + x2];
        }
    }
    h0[idx] = acc;
}

// ---------------- pointwise 256x256 GEMM + BN1 + leaky relu ----------------
__global__ __launch_bounds__(256) void pw_conv(const float* __restrict__ h0,
                                               const float* __restrict__ w,
                                               const float* __restrict__ g,
                                               const float* __restrict__ b,
                                               const float* __restrict__ mu,
                                               const float* __restrict__ var,
                                               float* __restrict__ h1) {
    int p = blockIdx.x * 256 + threadIdx.x;
    int o0 = blockIdx.y * 4;
    float acc0 = 0.f, acc1 = 0.f, acc2 = 0.f, acc3 = 0.f;
    for (int c = 0; c < 256; ++c) {
        float hv = h0[(c << 10) + p];
        acc0 += w[(o0 + 0) * 256 + c] * hv;
        acc1 += w[(o0 + 1) * 256 + c] * hv;
        acc2 += w[(o0 + 2) * 256 + c] * hv;
        acc3 += w[(o0 + 3) * 256 + c] * hv;
    }
    float accs[4] = {acc0, acc1, acc2, acc3};
    #pragma unroll
    for (int k = 0; k < 4; ++k) {
        int o = o0 + k;
        float inv = 1.0f / sqrtf(var[o] + EPSF);
        float v = (accs[k] - mu[o]) * (inv * g[o]) + b[o];
        v = (v >= 0.f) ? v : 0.01f * v;
        h1[(o << 10) + p] = v;
    }
}

// ---------------- heads: anc (36 ch) + obj (9 ch) GEMV + BN + decode ----------------
__global__ __launch_bounds__(256) void heads(const float* __restrict__ h1,
                                             const float* __restrict__ anc_w,
                                             const float* __restrict__ ag,
                                             const float* __restrict__ ab,
                                             const float* __restrict__ am,
                                             const float* __restrict__ av,
                                             const float* __restrict__ obj_w,
                                             const float* __restrict__ og,
                                             const float* __restrict__ ob,
                                             const float* __restrict__ om,
                                             const float* __restrict__ ov,
                                             const float* __restrict__ anchors,
                                             float* __restrict__ boxes,
                                             float* __restrict__ scores) {
    int p = blockIdx.x * 256 + threadIdx.x;
    int o = blockIdx.y;
    const float* wrow = (o < 36) ? (anc_w + o * 256) : (obj_w + (o - 36) * 256);
    float acc = 0.f;
    for (int c = 0; c < 256; ++c) acc += wrow[c] * h1[(c << 10) + p];
    if (o < 36) {
        float inv = 1.0f / sqrtf(av[o] + EPSF);
        float v = (acc - am[o]) * (inv * ag[o]) + ab[o];
        v = fminf(fmaxf(v, 0.f), 6.f);           // clip 0..6
        int a = o >> 2, k = o & 3;
        float anch = anchors[a * 4 + k];
        float val = (k < 2) ? (v + anch) : (expf(v) * anch);
        boxes[(size_t)(a * 1024 + p) * 4 + k] = val;
    } else {
        int a = o - 36;
        float inv = 1.0f / sqrtf(ov[a] + EPSF);
        float v = (acc - om[a]) * (inv * og[a]) + ob[a];
        scores[a * 1024 + p] = 1.0f / (1.0f + expf(-v));
    }
}

// ---------------- rank = stable-descending-argsort position, O(N^2) count ----------------
__global__ __launch_bounds__(256) void rank_partial(const float* __restrict__ scores,
                                                    unsigned* __restrict__ rank) {
    __shared__ float4 sm[288];
    int mbase = blockIdx.y * 1152;
    for (int t = threadIdx.x; t < 288; t += 256)
        sm[t] = ((const float4*)(scores + mbase))[t];
    __syncthreads();
    int n = blockIdx.x * 256 + threadIdx.x;
    float s = scores[n];
    unsigned cnt = 0;
    for (int q = 0; q < 288; ++q) {
        float4 v = sm[q];
        int m = mbase + q * 4;
        cnt += (v.x > s) || (v.x == s && (m + 0) < n);
        cnt += (v.y > s) || (v.y == s && (m + 1) < n);
        cnt += (v.z > s) || (v.z == s && (m + 2) < n);
        cnt += (v.w > s) || (v.w == s && (m + 3) < n);
    }
    atomicAdd(&rank[n], cnt);
}

// ---------------- scatter into sorted order ----------------
__global__ __launch_bounds__(256) void scatter_sorted(const float* __restrict__ boxes,
                                                      const unsigned* __restrict__ rank,
                                                      int* __restrict__ order,
                                                      float* __restrict__ sboxes,
                                                      float* __restrict__ sareas) {
    int n = blockIdx.x * 256 + threadIdx.x;
    unsigned r = rank[n];
    order[r] = n;
    float4 bx = ((const float4*)boxes)[n];
    ((float4*)sboxes)[r] = bx;
    sareas[r] = (bx.z - bx.x) * (bx.w - bx.y);
}

// ---------------- suppression bitmask, [row][word] layout ----------------
// mask[i*NWORDS + wj] bit t = row i suppresses row j0+t (j>i, IOU>thr)
// diag_g[i] = mask[i][i>>6]  (within-word suppression bits)
// rnz64[w] bit t = row w*64+t has ANY outgoing suppression bit
__global__ __launch_bounds__(256) void build_mask(const float* __restrict__ sboxes,
                                                  const float* __restrict__ sareas,
                                                  unsigned long long* __restrict__ mask,
                                                  unsigned long long* __restrict__ rnz64,
                                                  unsigned long long* __restrict__ diag_g) {
    __shared__ float X1[64], Y1[64], X2[64], Y2[64], AR[64];
    int wj = blockIdx.x;
    int i = blockIdx.y * 256 + threadIdx.x;
    int j0 = wj * 64;
    if (threadIdx.x < 64) {
        int j = j0 + threadIdx.x;
        float4 b = ((const float4*)sboxes)[j];
        X1[threadIdx.x] = b.x; Y1[threadIdx.x] = b.y;
        X2[threadIdx.x] = b.z; Y2[threadIdx.x] = b.w;
        AR[threadIdx.x] = sareas[j];
    }
    __syncthreads();
    unsigned long long wbits = 0ull;
    if (j0 + 63 > i) {   // word has at least one column j > i
        float4 b = ((const float4*)sboxes)[i];
        float ar = sareas[i];
        #pragma unroll 8
        for (int t = 0; t < 64; ++t) {
            float ix = fminf(b.z, X2[t]) - fmaxf(b.x, X1[t]);
            float iy = fminf(b.w, Y2[t]) - fmaxf(b.y, Y1[t]);
            float inter = fmaxf(ix, 0.f) * fmaxf(iy, 0.f);
            float iou = inter / (ar + AR[t] - inter);
            if (iou > IOU_THRF && (j0 + t) > i) wbits |= (1ull << t);
        }
    }
    mask[(size_t)i * NWORDS + wj] = wbits;
    if (wbits) atomicOr(&rnz64[i >> 6], 1ull << (i & 63));
    if (wj == (i >> 6)) diag_g[i] = wbits;
}

// ---------------- scalar word-granular greedy scan ----------------
__device__ inline unsigned long long rdl64(unsigned long long v, int l) {
    unsigned lo = (unsigned)__builtin_amdgcn_readlane((int)(unsigned)(v & 0xffffffffull), l);
    unsigned hi = (unsigned)__builtin_amdgcn_readlane((int)(unsigned)(v >> 32), l);
    return ((unsigned long long)hi << 32) | lo;
}

__global__ __launch_bounds__(64) void nms_scan(const unsigned long long* __restrict__ mask,
                                               const unsigned long long* __restrict__ rnz64,
                                               const unsigned long long* __restrict__ diag_g,
                                               unsigned long long* __restrict__ remv_out) {
    int lane = threadIdx.x;
    // candidate masks, distributed (3 slots: words lane, 64+lane, 128+lane)
    unsigned long long rz0 = rnz64[lane];
    unsigned long long rz1 = rnz64[64 + lane];
    unsigned long long rz2 = rnz64[128 + lane];   // rnz64 over-allocated to 192, zeroed
    // distributed removal bitmask
    unsigned long long r0 = 0ull, r1 = 0ull, r2 = 0ull;
    // pending fired-row ring, 8 named slots
    unsigned long long pa0=0,pb0=0,pc0=0, pa1=0,pb1=0,pc1=0, pa2=0,pb2=0,pc2=0, pa3=0,pb3=0,pc3=0;
    unsigned long long pa4=0,pb4=0,pc4=0, pa5=0,pb5=0,pc5=0, pa6=0,pb6=0,pc6=0, pa7=0,pb7=0,pc7=0;
    int npend = 0;

    auto drain = [&]() {
        if (npend > 0) { r0 |= pa0; r1 |= pb0; r2 |= pc0; }
        if (npend > 1) { r0 |= pa1; r1 |= pb1; r2 |= pc1; }
        if (npend > 2) { r0 |= pa2; r1 |= pb2; r2 |= pc2; }
        if (npend > 3) { r0 |= pa3; r1 |= pb3; r2 |= pc3; }
        if (npend > 4) { r0 |= pa4; r1 |= pb4; r2 |= pc4; }
        if (npend > 5) { r0 |= pa5; r1 |= pb5; r2 |= pc5; }
        if (npend > 6) { r0 |= pa6; r1 |= pb6; r2 |= pc6; }
        if (npend > 7) { r0 |= pa7; r1 |= pb7; r2 |= pc7; }
        npend = 0;
    };

    // diag prefetch rotation, 2 words ahead
    unsigned long long dgA = diag_g[0 * 64 + lane];
    unsigned long long dgB = diag_g[1 * 64 + lane];

    for (int w = 0; w < NWORDS; ++w) {
        int wp = w + 2; if (wp > NWORDS - 1) wp = NWORDS - 1;
        unsigned long long dgC = diag_g[wp * 64 + lane];

        int slot = w >> 6, src = w & 63;
        unsigned long long rz = (slot == 0) ? rdl64(rz0, src)
                              : (slot == 1) ? rdl64(rz1, src) : rdl64(rz2, src);
        if (rz) {
            if (npend) drain();   // retire fires from earlier words (waitcnt here)
            unsigned long long scur = (slot == 0) ? rdl64(r0, src)
                                    : (slot == 1) ? rdl64(r1, src) : rdl64(r2, src);
            unsigned long long cand = rz & ~scur;
            while (cand) {
                int t = __builtin_ctzll(cand);
                unsigned long long dv = rdl64(dgA, t);   // fired row's within-word bits
                scur |= dv;
                cand &= ~(1ull << t);
                cand &= ~dv;
                // issue full-row load into pending ring (coalesced: 18 lines)
                int i = (w << 6) + t;
                const unsigned long long* rowp = mask + (size_t)i * NWORDS;
                if (npend == 8) drain();
                switch (npend) {
                    case 0: pa0 = rowp[lane]; pb0 = rowp[64+lane]; pc0 = rowp[128+lane]; break;
                    case 1: pa1 = rowp[lane]; pb1 = rowp[64+lane]; pc1 = rowp[128+lane]; break;
                    case 2: pa2 = rowp[lane]; pb2 = rowp[64+lane]; pc2 = rowp[128+lane]; break;
                    case 3: pa3 = rowp[lane]; pb3 = rowp[64+lane]; pc3 = rowp[128+lane]; break;
                    case 4: pa4 = rowp[lane]; pb4 = rowp[64+lane]; pc4 = rowp[128+lane]; break;
                    case 5: pa5 = rowp[lane]; pb5 = rowp[64+lane]; pc5 = rowp[128+lane]; break;
                    case 6: pa6 = rowp[lane]; pb6 = rowp[64+lane]; pc6 = rowp[128+lane]; break;
                    default: pa7 = rowp[lane]; pb7 = rowp[64+lane]; pc7 = rowp[128+lane]; break;
                }
                ++npend;
            }
        }
        dgA = dgB; dgB = dgC;
    }
    if (npend) drain();
    // lanes >= 16 hold garbage in r2 (over-read of mask row tail) — never read
    remv_out[lane] = r0;
    remv_out[64 + lane] = r1;
    if (lane < 16) remv_out[128 + lane] = r2;
}

// ---------------- finalize: out[n] = {boxes*m, score*m} ----------------
__global__ __launch_bounds__(256) void finalize(const float* __restrict__ boxes,
                                                const float* __restrict__ scores,
                                                const int* __restrict__ order,
                                                const unsigned long long* __restrict__ remv,
                                                float* __restrict__ out) {
    int i = blockIdx.x * 256 + threadIdx.x;    // sorted index
    bool alive = ((remv[i >> 6] >> (i & 63)) & 1ull) == 0ull;
    int n = order[i];
    float m = alive ? 1.f : 0.f;
    float4 b = ((const float4*)boxes)[n];
    out[(size_t)n * 5 + 0] = b.x * m;
    out[(size_t)n * 5 + 1] = b.y * m;
    out[(size_t)n * 5 + 2] = b.z * m;
    out[(size_t)n * 5 + 3] = b.w * m;
    out[(size_t)n * 5 + 4] = scores[n] * m;
}

extern "C" void kernel_launch(void* const* d_in, const int* in_sizes, int n_in,
                              void* d_out, int out_size, void* d_ws, size_t ws_size,
                              hipStream_t stream) {
    const float* x      = (const float*)d_in[0];
    const float* anchors= (const float*)d_in[1];
    const float* dw_w   = (const float*)d_in[2];
    const float* pw_w   = (const float*)d_in[3];
    const float* bn1g   = (const float*)d_in[4];
    const float* bn1b   = (const float*)d_in[5];
    const float* bn1m   = (const float*)d_in[6];
    const float* bn1v   = (const float*)d_in[7];
    const float* anc_w  = (const float*)d_in[8];
    const float* ag     = (const float*)d_in[9];
    const float* ab     = (const float*)d_in[10];
    const float* am     = (const float*)d_in[11];
    const float* av     = (const float*)d_in[12];
    const float* obj_w  = (const float*)d_in[13];
    const float* og     = (const float*)d_in[14];
    const float* ob     = (const float*)d_in[15];
    const float* om     = (const float*)d_in[16];
    const float* ov     = (const float*)d_in[17];
    float* out = (float*)d_out;

    char* ws = (char*)d_ws;
    size_t off = 0;
    auto alloc = [&](size_t bytes) -> char* {
        char* p = ws + off;
        off = (off + bytes + 255) & ~(size_t)255;
        return p;
    };
    float* h0      = (float*)alloc(256 * 1024 * 4);
    float* h1      = (float*)alloc(256 * 1024 * 4);
    float* boxes   = (float*)alloc(NBOX * 4 * 4);
    float* scores  = (float*)alloc(NBOX * 4);
    unsigned* rank = (unsigned*)alloc(NBOX * 4);
    int* order     = (int*)alloc(NBOX * 4);
    float* sboxes  = (float*)alloc(NBOX * 4 * 4);
    float* sareas  = (float*)alloc(NBOX * 4);
    unsigned long long* remv  = (unsigned long long*)alloc(NWORDS * 8);
    unsigned long long* rnz64 = (unsigned long long*)alloc(192 * 8);
    unsigned long long* diag  = (unsigned long long*)alloc(NBOX * 8);
    // +1 extra row: scan over-reads words 144..191 of a row (harmless lanes)
    unsigned long long* mask  = (unsigned long long*)alloc((size_t)(NBOX + 1) * NWORDS * 8);

    hipMemsetAsync(rank, 0, NBOX * 4, stream);
    hipMemsetAsync(rnz64, 0, 192 * 8, stream);

    dw_conv<<<1024, 256, 0, stream>>>(x, dw_w, h0);
    pw_conv<<<dim3(4, 64), 256, 0, stream>>>(h0, pw_w, bn1g, bn1b, bn1m, bn1v, h1);
    heads<<<dim3(4, 45), 256, 0, stream>>>(h1, anc_w, ag, ab, am, av,
                                           obj_w, og, ob, om, ov, anchors, boxes, scores);
    rank_partial<<<dim3(36, 8), 256, 0, stream>>>(scores, rank);
    scatter_sorted<<<36, 256, 0, stream>>>(boxes, rank, order, sboxes, sareas);
    build_mask<<<dim3(NWORDS, 36), 256, 0, stream>>>(sboxes, sareas, mask, rnz64, diag);
    nms_scan<<<1, 64, 0, stream>>>(mask, rnz64, diag, remv);
    finalize<<<36, 256, 0, stream>>>(boxes, scores, order, remv, out);
}

// Round 5
// 407.678 us; speedup vs baseline: 3.8639x; 1.6624x over previous
//
#include <hip/hip_runtime.h>
#include <hip/hip_bf16.h>

#define EPSF 1e-5f
#define IOU_THRF 0.9f
#define NBOX 9216
#define NWORDS 144   // 9216/64

// ---------------- depthwise 3x3 conv, C=256, 32x32, pad 1 ----------------
__global__ __launch_bounds__(256) void dw_conv(const float* __restrict__ x,
                                               const float* __restrict__ w,
                                               float* __restrict__ h0) {
    int idx = blockIdx.x * 256 + threadIdx.x;   // 262144 threads
    int c = idx >> 10, p = idx & 1023;
    int yy = p >> 5, xx = p & 31;
    const float* xi = x + (c << 10);
    const float* wc = w + c * 9;
    float acc = 0.f;
    #pragma unroll
    for (int dy = -1; dy <= 1; ++dy) {
        int y2 = yy + dy;
        if ((unsigned)y2 >= 32u) continue;
        #pragma unroll
        for (int dx = -1; dx <= 1; ++dx) {
            int x2 = xx + dx;
            if ((unsigned)x2 >= 32u) continue;
            acc += wc[(dy + 1) * 3 + (dx + 1)] * xi[y2 * 32 + x2];
        }
    }
    h0[idx] = acc;
}

// ---------------- pointwise 256x256 GEMM + BN1 + leaky relu ----------------
__global__ __launch_bounds__(256) void pw_conv(const float* __restrict__ h0,
                                               const float* __restrict__ w,
                                               const float* __restrict__ g,
                                               const float* __restrict__ b,
                                               const float* __restrict__ mu,
                                               const float* __restrict__ var,
                                               float* __restrict__ h1) {
    int p = blockIdx.x * 256 + threadIdx.x;
    int o0 = blockIdx.y * 4;
    float acc0 = 0.f, acc1 = 0.f, acc2 = 0.f, acc3 = 0.f;
    for (int c = 0; c < 256; ++c) {
        float hv = h0[(c << 10) + p];
        acc0 += w[(o0 + 0) * 256 + c] * hv;
        acc1 += w[(o0 + 1) * 256 + c] * hv;
        acc2 += w[(o0 + 2) * 256 + c] * hv;
        acc3 += w[(o0 + 3) * 256 + c] * hv;
    }
    float accs[4] = {acc0, acc1, acc2, acc3};
    #pragma unroll
    for (int k = 0; k < 4; ++k) {
        int o = o0 + k;
        float inv = 1.0f / sqrtf(var[o] + EPSF);
        float v = (accs[k] - mu[o]) * (inv * g[o]) + b[o];
        v = (v >= 0.f) ? v : 0.01f * v;
        h1[(o << 10) + p] = v;
    }
}

// ---------------- heads: anc (36 ch) + obj (9 ch) GEMV + BN + decode ----------------
__global__ __launch_bounds__(256) void heads(const float* __restrict__ h1,
                                             const float* __restrict__ anc_w,
                                             const float* __restrict__ ag,
                                             const float* __restrict__ ab,
                                             const float* __restrict__ am,
                                             const float* __restrict__ av,
                                             const float* __restrict__ obj_w,
                                             const float* __restrict__ og,
                                             const float* __restrict__ ob,
                                             const float* __restrict__ om,
                                             const float* __restrict__ ov,
                                             const float* __restrict__ anchors,
                                             float* __restrict__ boxes,
                                             float* __restrict__ scores) {
    int p = blockIdx.x * 256 + threadIdx.x;
    int o = blockIdx.y;
    const float* wrow = (o < 36) ? (anc_w + o * 256) : (obj_w + (o - 36) * 256);
    float acc = 0.f;
    for (int c = 0; c < 256; ++c) acc += wrow[c] * h1[(c << 10) + p];
    if (o < 36) {
        float inv = 1.0f / sqrtf(av[o] + EPSF);
        float v = (acc - am[o]) * (inv * ag[o]) + ab[o];
        v = fminf(fmaxf(v, 0.f), 6.f);           // clip 0..6
        int a = o >> 2, k = o & 3;
        float anch = anchors[a * 4 + k];
        float val = (k < 2) ? (v + anch) : (expf(v) * anch);
        boxes[(size_t)(a * 1024 + p) * 4 + k] = val;
    } else {
        int a = o - 36;
        float inv = 1.0f / sqrtf(ov[a] + EPSF);
        float v = (acc - om[a]) * (inv * og[a]) + ob[a];
        scores[a * 1024 + p] = 1.0f / (1.0f + expf(-v));
    }
}

// ---------------- rank = stable-descending-argsort position, O(N^2) count ----------------
__global__ __launch_bounds__(256) void rank_partial(const float* __restrict__ scores,
                                                    unsigned* __restrict__ rank) {
    __shared__ float4 sm[288];
    int mbase = blockIdx.y * 1152;
    for (int t = threadIdx.x; t < 288; t += 256)
        sm[t] = ((const float4*)(scores + mbase))[t];
    __syncthreads();
    int n = blockIdx.x * 256 + threadIdx.x;
    float s = scores[n];
    unsigned cnt = 0;
    for (int q = 0; q < 288; ++q) {
        float4 v = sm[q];
        int m = mbase + q * 4;
        cnt += (v.x > s) || (v.x == s && (m + 0) < n);
        cnt += (v.y > s) || (v.y == s && (m + 1) < n);
        cnt += (v.z > s) || (v.z == s && (m + 2) < n);
        cnt += (v.w > s) || (v.w == s && (m + 3) < n);
    }
    atomicAdd(&rank[n], cnt);
}

// ---------------- scatter into sorted order ----------------
__global__ __launch_bounds__(256) void scatter_sorted(const float* __restrict__ boxes,
                                                      const unsigned* __restrict__ rank,
                                                      int* __restrict__ order,
                                                      float* __restrict__ sboxes,
                                                      float* __restrict__ sareas) {
    int n = blockIdx.x * 256 + threadIdx.x;
    unsigned r = rank[n];
    order[r] = n;
    float4 bx = ((const float4*)boxes)[n];
    ((float4*)sboxes)[r] = bx;
    sareas[r] = (bx.z - bx.x) * (bx.w - bx.y);
}

// ---------------- suppression bitmask, [row][word] layout, coalesced ----------------
// grid (18 stripes of 8 words/512 cols, 36 row-blocks of 256 rows), 256 thr.
// Each thread computes one row x 8 words; LDS transpose makes the global
// write fully coalesced (8 lanes = one 64B line).
__global__ __launch_bounds__(256) void build_mask(const float* __restrict__ sboxes,
                                                  const float* __restrict__ sareas,
                                                  unsigned long long* __restrict__ mask,
                                                  unsigned long long* __restrict__ rnz64,
                                                  unsigned long long* __restrict__ diag_g) {
    __shared__ float CX1[512], CY1[512], CX2[512], CY2[512], CAR[512];
    __shared__ unsigned long long tile[8][258];   // pad 258: conflict-free transposed read
    int s  = blockIdx.x;          // stripe: words 8s..8s+7
    int rb = blockIdx.y;          // rows 256rb..256rb+255
    int tid = threadIdx.x;
    int i = rb * 256 + tid;

    #pragma unroll
    for (int k = 0; k < 2; ++k) {
        int idx = tid + k * 256;
        int j = s * 512 + idx;
        float4 b = ((const float4*)sboxes)[j];
        CX1[idx] = b.x; CY1[idx] = b.y; CX2[idx] = b.z; CY2[idx] = b.w;
        CAR[idx] = sareas[j];
    }
    __syncthreads();

    float4 b = ((const float4*)sboxes)[i];
    float ar = sareas[i];
    unsigned long long row_or = 0ull, dval = 0ull;
    int mydiag = i >> 6;

    #pragma unroll
    for (int wloc = 0; wloc < 8; ++wloc) {
        unsigned long long bits = 0ull;
        int jbase = s * 512 + wloc * 64;
        #pragma unroll 8
        for (int t = 0; t < 64; ++t) {
            int idx = wloc * 64 + t;
            float ix = fminf(b.z, CX2[idx]) - fmaxf(b.x, CX1[idx]);
            float iy = fminf(b.w, CY2[idx]) - fmaxf(b.y, CY1[idx]);
            float inter = fmaxf(ix, 0.f) * fmaxf(iy, 0.f);
            float iou = inter / (ar + CAR[idx] - inter);
            if (iou > IOU_THRF && (jbase + t) > i) bits |= (1ull << t);
        }
        tile[wloc][tid] = bits;
        row_or |= bits;
        if (s * 8 + wloc == mydiag) dval = bits;
    }

    // rnz64: one ballot per wave (wave owns rows of exactly one rnz word)
    unsigned long long bal = __ballot(row_or != 0ull);
    if ((tid & 63) == 0)
        atomicOr(&rnz64[rb * 4 + (tid >> 6)], bal);
    if (s == (rb >> 1)) diag_g[i] = dval;

    __syncthreads();
    // transposed write: 8 consecutive lanes emit one full 64B line
    int k = tid & 7, rbase = tid >> 3;
    #pragma unroll
    for (int it = 0; it < 8; ++it) {
        int r = rbase + it * 32;
        mask[(size_t)(rb * 256 + r) * NWORDS + s * 8 + k] = tile[k][r];
    }
}

// ---------------- scalar word-granular greedy scan ----------------
__device__ inline unsigned long long rdl64(unsigned long long v, int l) {
    unsigned lo = (unsigned)__builtin_amdgcn_readlane((int)(unsigned)(v & 0xffffffffull), l);
    unsigned hi = (unsigned)__builtin_amdgcn_readlane((int)(unsigned)(v >> 32), l);
    return ((unsigned long long)hi << 32) | lo;
}

__global__ __launch_bounds__(64) void nms_scan(const unsigned long long* __restrict__ mask,
                                               const unsigned long long* __restrict__ rnz64,
                                               const unsigned long long* __restrict__ diag_g,
                                               unsigned long long* __restrict__ remv_out) {
    int lane = threadIdx.x;
    unsigned long long rz0 = rnz64[lane];
    unsigned long long rz1 = rnz64[64 + lane];
    unsigned long long rz2 = rnz64[128 + lane];   // 144..191 zeroed
    unsigned long long r0 = 0ull, r1 = 0ull, r2 = 0ull;
    unsigned long long pa0=0,pb0=0,pc0=0, pa1=0,pb1=0,pc1=0, pa2=0,pb2=0,pc2=0, pa3=0,pb3=0,pc3=0;
    unsigned long long pa4=0,pb4=0,pc4=0, pa5=0,pb5=0,pc5=0, pa6=0,pb6=0,pc6=0, pa7=0,pb7=0,pc7=0;
    int npend = 0;

    auto drain = [&]() {
        if (npend > 0) { r0 |= pa0; r1 |= pb0; r2 |= pc0; }
        if (npend > 1) { r0 |= pa1; r1 |= pb1; r2 |= pc1; }
        if (npend > 2) { r0 |= pa2; r1 |= pb2; r2 |= pc2; }
        if (npend > 3) { r0 |= pa3; r1 |= pb3; r2 |= pc3; }
        if (npend > 4) { r0 |= pa4; r1 |= pb4; r2 |= pc4; }
        if (npend > 5) { r0 |= pa5; r1 |= pb5; r2 |= pc5; }
        if (npend > 6) { r0 |= pa6; r1 |= pb6; r2 |= pc6; }
        if (npend > 7) { r0 |= pa7; r1 |= pb7; r2 |= pc7; }
        npend = 0;
    };

    unsigned long long dgA = diag_g[0 * 64 + lane];
    unsigned long long dgB = diag_g[1 * 64 + lane];

    for (int w = 0; w < NWORDS; ++w) {
        int wp = w + 2; if (wp > NWORDS - 1) wp = NWORDS - 1;
        unsigned long long dgC = diag_g[wp * 64 + lane];

        int slot = w >> 6, src = w & 63;
        unsigned long long rz = (slot == 0) ? rdl64(rz0, src)
                              : (slot == 1) ? rdl64(rz1, src) : rdl64(rz2, src);
        if (rz) {
            if (npend) drain();
            unsigned long long scur = (slot == 0) ? rdl64(r0, src)
                                    : (slot == 1) ? rdl64(r1, src) : rdl64(r2, src);
            unsigned long long cand = rz & ~scur;
            while (cand) {
                int t = __builtin_ctzll(cand);
                unsigned long long dv = rdl64(dgA, t);
                scur |= dv;
                cand &= ~(1ull << t);
                cand &= ~dv;
                int i = (w << 6) + t;
                const unsigned long long* rowp = mask + (size_t)i * NWORDS;
                if (npend == 8) drain();
                switch (npend) {
                    case 0: pa0 = rowp[lane]; pb0 = rowp[64+lane]; pc0 = rowp[128+lane]; break;
                    case 1: pa1 = rowp[lane]; pb1 = rowp[64+lane]; pc1 = rowp[128+lane]; break;
                    case 2: pa2 = rowp[lane]; pb2 = rowp[64+lane]; pc2 = rowp[128+lane]; break;
                    case 3: pa3 = rowp[lane]; pb3 = rowp[64+lane]; pc3 = rowp[128+lane]; break;
                    case 4: pa4 = rowp[lane]; pb4 = rowp[64+lane]; pc4 = rowp[128+lane]; break;
                    case 5: pa5 = rowp[lane]; pb5 = rowp[64+lane]; pc5 = rowp[128+lane]; break;
                    case 6: pa6 = rowp[lane]; pb6 = rowp[64+lane]; pc6 = rowp[128+lane]; break;
                    default: pa7 = rowp[lane]; pb7 = rowp[64+lane]; pc7 = rowp[128+lane]; break;
                }
                ++npend;
            }
        }
        dgA = dgB; dgB = dgC;
    }
    if (npend) drain();
    remv_out[lane] = r0;
    remv_out[64 + lane] = r1;
    if (lane < 16) remv_out[128 + lane] = r2;
}

// ---------------- finalize: out[n] = {boxes*m, score*m} ----------------
__global__ __launch_bounds__(256) void finalize(const float* __restrict__ boxes,
                                                const float* __restrict__ scores,
                                                const int* __restrict__ order,
                                                const unsigned long long* __restrict__ remv,
                                                float* __restrict__ out) {
    int i = blockIdx.x * 256 + threadIdx.x;    // sorted index
    bool alive = ((remv[i >> 6] >> (i & 63)) & 1ull) == 0ull;
    int n = order[i];
    float m = alive ? 1.f : 0.f;
    float4 b = ((const float4*)boxes)[n];
    out[(size_t)n * 5 + 0] = b.x * m;
    out[(size_t)n * 5 + 1] = b.y * m;
    out[(size_t)n * 5 + 2] = b.z * m;
    out[(size_t)n * 5 + 3] = b.w * m;
    out[(size_t)n * 5 + 4] = scores[n] * m;
}

extern "C" void kernel_launch(void* const* d_in, const int* in_sizes, int n_in,
                              void* d_out, int out_size, void* d_ws, size_t ws_size,
                              hipStream_t stream) {
    const float* x      = (const float*)d_in[0];
    const float* anchors= (const float*)d_in[1];
    const float* dw_w   = (const float*)d_in[2];
    const float* pw_w   = (const float*)d_in[3];
    const float* bn1g   = (const float*)d_in[4];
    const float* bn1b   = (const float*)d_in[5];
    const float* bn1m   = (const float*)d_in[6];
    const float* bn1v   = (const float*)d_in[7];
    const float* anc_w  = (const float*)d_in[8];
    const float* ag     = (const float*)d_in[9];
    const float* ab     = (const float*)d_in[10];
    const float* am     = (const float*)d_in[11];
    const float* av     = (const float*)d_in[12];
    const float* obj_w  = (const float*)d_in[13];
    const float* og     = (const float*)d_in[14];
    const float* ob     = (const float*)d_in[15];
    const float* om     = (const float*)d_in[16];
    const float* ov     = (const float*)d_in[17];
    float* out = (float*)d_out;

    char* ws = (char*)d_ws;
    size_t off = 0;
    auto alloc = [&](size_t bytes) -> char* {
        char* p = ws + off;
        off = (off + bytes + 255) & ~(size_t)255;
        return p;
    };
    float* h0      = (float*)alloc(256 * 1024 * 4);
    float* h1      = (float*)alloc(256 * 1024 * 4);
    float* boxes   = (float*)alloc(NBOX * 4 * 4);
    float* scores  = (float*)alloc(NBOX * 4);
    unsigned* rank = (unsigned*)alloc(NBOX * 4);
    int* order     = (int*)alloc(NBOX * 4);
    float* sboxes  = (float*)alloc(NBOX * 4 * 4);
    float* sareas  = (float*)alloc(NBOX * 4);
    unsigned long long* remv  = (unsigned long long*)alloc(NWORDS * 8);
    unsigned long long* rnz64 = (unsigned long long*)alloc(192 * 8);
    unsigned long long* diag  = (unsigned long long*)alloc(NBOX * 8);
    // +1 extra row: scan over-reads words 144..191 of a row (harmless lanes)
    unsigned long long* mask  = (unsigned long long*)alloc((size_t)(NBOX + 1) * NWORDS * 8);

    hipMemsetAsync(rank, 0, NBOX * 4, stream);
    hipMemsetAsync(rnz64, 0, 192 * 8, stream);

    dw_conv<<<1024, 256, 0, stream>>>(x, dw_w, h0);
    pw_conv<<<dim3(4, 64), 256, 0, stream>>>(h0, pw_w, bn1g, bn1b, bn1m, bn1v, h1);
    heads<<<dim3(4, 45), 256, 0, stream>>>(h1, anc_w, ag, ab, am, av,
                                           obj_w, og, ob, om, ov, anchors, boxes, scores);
    rank_partial<<<dim3(36, 8), 256, 0, stream>>>(scores, rank);
    scatter_sorted<<<36, 256, 0, stream>>>(boxes, rank, order, sboxes, sareas);
    build_mask<<<dim3(18, 36), 256, 0, stream>>>(sboxes, sareas, mask, rnz64, diag);
    nms_scan<<<1, 64, 0, stream>>>(mask, rnz64, diag, remv);
    finalize<<<36, 256, 0, stream>>>(boxes, scores, order, remv, out);
}